// Round 2
// baseline (163.809 us; speedup 1.0000x reference)
//
#include <hip/hip_runtime.h>

#define TILE      64
#define NTHREADS  256
#define STRIDE    85      // 5 + NUM_CLASSES
#define SSPAN     2704    // 52*52
#define MAXGRID   2028
#define PF4       ((TILE*STRIDE)/4)   // 1360 float4 per pred tile
#define TF4       ((TILE*6)/4)        // 96 float4 per tgt tile

__device__ __forceinline__ float wave_reduce(float v) {
    #pragma unroll
    for (int off = 32; off > 0; off >>= 1)
        v += __shfl_down(v, off, 64);
    return v;
}

__global__ __launch_bounds__(NTHREADS) void loss_partial(
    const float* __restrict__ pred, const float* __restrict__ tgt,
    const float* __restrict__ anchors, float* __restrict__ partial,
    int n_full, int n_rem)
{
    __shared__ float lds_p[TILE * STRIDE];   // 21.25 KB
    __shared__ float lds_t[TILE * 6];
    __shared__ float red[4][6];

    const int tid    = threadIdx.x;
    const int lane   = tid & 63;
    const int wid    = tid >> 6;
    const int cell_l = tid >> 2;
    const int part   = tid & 3;

    // anchors: 6 uniform floats, hoisted once
    const float aw0 = anchors[0], ah0 = anchors[1];
    const float aw1 = anchors[2], ah1 = anchors[3];
    const float aw2 = anchors[4], ah2 = anchors[5];

    float a_obj = 0.f, a_nobj = 0.f, a_bceo = 0.f, a_bceno = 0.f,
          a_box = 0.f, a_cls = 0.f;

    float4 rp[6];
    float4 rt;

    // ---- register prefetch of one full tile ----
    auto prefetch = [&](int t) {
        const float4* gp = (const float4*)(pred + (size_t)t * (TILE * STRIDE));
        #pragma unroll
        for (int j = 0; j < 5; ++j) rp[j] = gp[tid + j * NTHREADS];
        if (tid < PF4 - 5 * NTHREADS) rp[5] = gp[tid + 5 * NTHREADS];
        const float4* gt = (const float4*)(tgt + (size_t)t * (TILE * 6));
        if (tid < TF4) rt = gt[tid];
    };
    auto stow = [&]() {
        float4* lp = (float4*)lds_p;
        #pragma unroll
        for (int j = 0; j < 5; ++j) lp[tid + j * NTHREADS] = rp[j];
        if (tid < PF4 - 5 * NTHREADS) lp[tid + 5 * NTHREADS] = rp[5];
        if (tid < TF4) ((float4*)lds_t)[tid] = rt;
    };

    int t = blockIdx.x;
    if (t < n_full) prefetch(t);

    for (; t < n_full; t += gridDim.x) {
        __syncthreads();            // previous compute done -> LDS reusable
        stow();
        const int tn = t + gridDim.x;
        if (tn < n_full) prefetch(tn);   // in flight during barrier+compute
        __syncthreads();            // LDS tile visible

        // ---- class softmax partials: 20 logits/thread in registers ----
        const float* cp = lds_p + cell_l * STRIDE + 5 + part * 20;
        float v[20];
        #pragma unroll
        for (int k = 0; k < 20; ++k) v[k] = cp[k];
        float mx = v[0];
        #pragma unroll
        for (int k = 1; k < 20; ++k) mx = fmaxf(mx, v[k]);
        mx = fmaxf(mx, __shfl_xor(mx, 1, 64));
        mx = fmaxf(mx, __shfl_xor(mx, 2, 64));
        float se = 0.f;
        #pragma unroll
        for (int k = 0; k < 20; ++k) se += __expf(v[k] - mx);
        se += __shfl_xor(se, 1, 64);
        se += __shfl_xor(se, 2, 64);

        if (part == 0) {
            const float* pc = lds_p + cell_l * STRIDE;
            const float* tc = lds_t + cell_l * 6;
            const float p0 = pc[0], t0 = tc[0];
            const float bce_base = fmaxf(p0, 0.f) + log1pf(__expf(-fabsf(p0)));
            if (t0 == 0.0f) { a_nobj += 1.f; a_bceno += bce_base; }
            if (t0 == 1.0f) {
                a_obj += 1.f;
                const int cell_g = t * TILE + cell_l;
                const int aidx = (cell_g / SSPAN) % 3;
                const float aw = aidx == 0 ? aw0 : (aidx == 1 ? aw1 : aw2);
                const float ah = aidx == 0 ? ah0 : (aidx == 1 ? ah1 : ah2);
                const float p1 = pc[1], p2 = pc[2], p3 = pc[3], p4 = pc[4];
                const float t1 = tc[1], t2 = tc[2], t3 = tc[3], t4 = tc[4];
                const float sx = 1.f / (1.f + __expf(-p1));
                const float sy = 1.f / (1.f + __expf(-p2));
                const float pw = __expf(p3) * aw, ph = __expf(p4) * ah;
                const float b1x1 = sx - pw * 0.5f, b1x2 = sx + pw * 0.5f;
                const float b1y1 = sy - ph * 0.5f, b1y2 = sy + ph * 0.5f;
                const float b2x1 = t1 - t3 * 0.5f, b2x2 = t1 + t3 * 0.5f;
                const float b2y1 = t2 - t4 * 0.5f, b2y2 = t2 + t4 * 0.5f;
                const float iw = fmaxf(fminf(b1x2, b2x2) - fmaxf(b1x1, b2x1), 0.f);
                const float ih = fmaxf(fminf(b1y2, b2y2) - fmaxf(b1y1, b2y1), 0.f);
                const float inter = iw * ih;
                const float uni = (b1x2 - b1x1) * (b1y2 - b1y1)
                                + (b2x2 - b2x1) * (b2y2 - b2y1) - inter;
                const float iou = inter / (uni + 1e-16f);
                a_bceo += bce_base - p0 * iou;
                const float lw = logf(1e-16f + t3 / aw);
                const float lh = logf(1e-16f + t4 / ah);
                const float d0 = sx - t1, d1 = sy - t2, d2 = p3 - lw, d3 = p4 - lh;
                a_box += d0 * d0 + d1 * d1 + d2 * d2 + d3 * d3;
                const int label = (int)tc[5];
                a_cls += (mx + __logf(se)) - pc[5 + label];
            }
        }
    }

    // ---- tail cells (n_rem < 64): block 0 only, direct global reads ----
    if (blockIdx.x == 0 && n_rem > 0 && cell_l < n_rem) {
        const int cell_g = n_full * TILE + cell_l;
        const float* cp = pred + (size_t)cell_g * STRIDE + 5 + part * 20;
        float v[20];
        #pragma unroll
        for (int k = 0; k < 20; ++k) v[k] = cp[k];
        float mx = v[0];
        #pragma unroll
        for (int k = 1; k < 20; ++k) mx = fmaxf(mx, v[k]);
        mx = fmaxf(mx, __shfl_xor(mx, 1, 64));
        mx = fmaxf(mx, __shfl_xor(mx, 2, 64));
        float se = 0.f;
        #pragma unroll
        for (int k = 0; k < 20; ++k) se += __expf(v[k] - mx);
        se += __shfl_xor(se, 1, 64);
        se += __shfl_xor(se, 2, 64);
        if (part == 0) {
            const float* pc = pred + (size_t)cell_g * STRIDE;
            const float* tc = tgt + (size_t)cell_g * 6;
            const float p0 = pc[0], t0 = tc[0];
            const float bce_base = fmaxf(p0, 0.f) + log1pf(__expf(-fabsf(p0)));
            if (t0 == 0.0f) { a_nobj += 1.f; a_bceno += bce_base; }
            if (t0 == 1.0f) {
                a_obj += 1.f;
                const int aidx = (cell_g / SSPAN) % 3;
                const float aw = aidx == 0 ? aw0 : (aidx == 1 ? aw1 : aw2);
                const float ah = aidx == 0 ? ah0 : (aidx == 1 ? ah1 : ah2);
                const float p1 = pc[1], p2 = pc[2], p3 = pc[3], p4 = pc[4];
                const float t1 = tc[1], t2 = tc[2], t3 = tc[3], t4 = tc[4];
                const float sx = 1.f / (1.f + __expf(-p1));
                const float sy = 1.f / (1.f + __expf(-p2));
                const float pw = __expf(p3) * aw, ph = __expf(p4) * ah;
                const float b1x1 = sx - pw * 0.5f, b1x2 = sx + pw * 0.5f;
                const float b1y1 = sy - ph * 0.5f, b1y2 = sy + ph * 0.5f;
                const float b2x1 = t1 - t3 * 0.5f, b2x2 = t1 + t3 * 0.5f;
                const float b2y1 = t2 - t4 * 0.5f, b2y2 = t2 + t4 * 0.5f;
                const float iw = fmaxf(fminf(b1x2, b2x2) - fmaxf(b1x1, b2x1), 0.f);
                const float ih = fmaxf(fminf(b1y2, b2y2) - fmaxf(b1y1, b2y1), 0.f);
                const float inter = iw * ih;
                const float uni = (b1x2 - b1x1) * (b1y2 - b1y1)
                                + (b2x2 - b2x1) * (b2y2 - b2y1) - inter;
                const float iou = inter / (uni + 1e-16f);
                a_bceo += bce_base - p0 * iou;
                const float lw = logf(1e-16f + t3 / aw);
                const float lh = logf(1e-16f + t4 / ah);
                const float d0 = sx - t1, d1 = sy - t2, d2 = p3 - lw, d3 = p4 - lh;
                a_box += d0 * d0 + d1 * d1 + d2 * d2 + d3 * d3;
                const int label = (int)tc[5];
                a_cls += (mx + __logf(se)) - pc[5 + label];
            }
        }
    }

    // ---- block reduction -> per-block partial ----
    float vals[6] = {a_obj, a_nobj, a_bceo, a_bceno, a_box, a_cls};
    #pragma unroll
    for (int k = 0; k < 6; ++k) {
        const float r = wave_reduce(vals[k]);
        if (lane == 0) red[wid][k] = r;
    }
    __syncthreads();
    if (tid == 0) {
        #pragma unroll
        for (int k = 0; k < 6; ++k)
            partial[blockIdx.x * 6 + k] =
                red[0][k] + red[1][k] + red[2][k] + red[3][k];
    }
}

__global__ __launch_bounds__(NTHREADS) void loss_final(
    const float* __restrict__ partial, int nblocks, float* __restrict__ out)
{
    __shared__ float red[4][6];
    const int tid = threadIdx.x, lane = tid & 63, wid = tid >> 6;
    float s[6] = {0.f, 0.f, 0.f, 0.f, 0.f, 0.f};
    for (int i = tid; i < nblocks; i += NTHREADS) {
        #pragma unroll
        for (int k = 0; k < 6; ++k) s[k] += partial[i * 6 + k];
    }
    #pragma unroll
    for (int k = 0; k < 6; ++k) {
        const float r = wave_reduce(s[k]);
        if (lane == 0) red[wid][k] = r;
    }
    __syncthreads();
    if (tid == 0) {
        float t[6];
        #pragma unroll
        for (int k = 0; k < 6; ++k)
            t[k] = red[0][k] + red[1][k] + red[2][k] + red[3][k];
        const float n_obj = t[0], n_noobj = t[1];
        out[0] = t[2] / n_obj + t[3] / n_noobj
               + t[4] / (4.f * n_obj) + t[5] / n_obj;
    }
}

extern "C" void kernel_launch(void* const* d_in, const int* in_sizes, int n_in,
                              void* d_out, int out_size, void* d_ws, size_t ws_size,
                              hipStream_t stream) {
    const float* pred    = (const float*)d_in[0];
    const float* tgt     = (const float*)d_in[1];
    const float* anchors = (const float*)d_in[2];
    float* out = (float*)d_out;

    const int n_cells = in_sizes[1] / 6;          // 259584
    const int n_full  = n_cells / TILE;           // 4056
    const int n_rem   = n_cells % TILE;           // 0 for this shape
    const int grid = n_full < MAXGRID ? (n_full > 0 ? n_full : 1) : MAXGRID;
    float* partial = (float*)d_ws;

    loss_partial<<<grid, NTHREADS, 0, stream>>>(pred, tgt, anchors, partial,
                                                n_full, n_rem);
    loss_final<<<1, NTHREADS, 0, stream>>>(partial, grid, out);
}

// Round 3
// 142.952 us; speedup vs baseline: 1.1459x; 1.1459x over previous
//
#include <hip/hip_runtime.h>

#define TILE      64
#define NTHREADS  256
#define STRIDE    85            // 5 + NUM_CLASSES
#define SSPAN     2704          // 52*52
#define MAXGRID   768           // 3 blocks/CU * 256 CU
#define PRED_F4_T 1360          // float4 slots per pred tile (64*85/4)
#define TGT_F4_T  96            // float4 slots per tgt tile (64*6/4)
#define TOT_F4    1456          // combined useful slots
#define NCALLS    6             // 6*256 = 1536 slots staged per tile (80 pad)
#define SLOTS     (NCALLS*NTHREADS)
#define BUF_FLOATS (SLOTS*4)    // 6144 floats = 24 KB per buffer
#define LDS_T_OFF (PRED_F4_T*4) // float offset of tgt slab inside buffer

typedef __attribute__((address_space(1))) const void gas_void;
typedef __attribute__((address_space(3))) void las_void;

__device__ __forceinline__ float wave_reduce(float v) {
    #pragma unroll
    for (int off = 32; off > 0; off >>= 1)
        v += __shfl_down(v, off, 64);
    return v;
}

// Stage one tile (pred 1360 f4 + tgt 96 f4 + 80 pad slots) into LDS buffer
// via async DMA. Every thread issues exactly NCALLS loads -> uniform vmcnt.
__device__ __forceinline__ void stage_tile(
    const float* __restrict__ pred, const float* __restrict__ tgt,
    int t, float* buf, int tid)
{
    const float* pbase = pred + (size_t)t * (TILE * STRIDE);
    const float* tbase = tgt  + (size_t)t * (TILE * 6);
    #pragma unroll
    for (int c = 0; c < NCALLS; ++c) {
        const int s = c * NTHREADS + tid;
        const float* src;
        if (s < PRED_F4_T)   src = pbase + (size_t)s * 4;
        else if (s < TOT_F4) src = tbase + (size_t)(s - PRED_F4_T) * 4;
        else                 src = tbase;            // pad slot: safe re-read
        __builtin_amdgcn_global_load_lds((gas_void*)src,
                                         (las_void*)(buf + (size_t)s * 4),
                                         16, 0, 0);
    }
}

__global__ __launch_bounds__(NTHREADS) void loss_partial(
    const float* __restrict__ pred, const float* __restrict__ tgt,
    const float* __restrict__ anchors, float* __restrict__ partial,
    int n_full, int n_rem)
{
    __shared__ float buf[2][BUF_FLOATS];   // 48 KB double buffer
    __shared__ float red[4][6];

    const int tid    = threadIdx.x;
    const int lane   = tid & 63;
    const int wid    = tid >> 6;
    const int cell_l = tid >> 2;
    const int part   = tid & 3;

    const float aw0 = anchors[0], ah0 = anchors[1];
    const float aw1 = anchors[2], ah1 = anchors[3];
    const float aw2 = anchors[4], ah2 = anchors[5];

    float a_obj = 0.f, a_nobj = 0.f, a_bceo = 0.f, a_bceno = 0.f,
          a_box = 0.f, a_cls = 0.f;

    int t = blockIdx.x;
    const int gstride = gridDim.x;
    if (t < n_full) stage_tile(pred, tgt, t, buf[0], tid);
    int cur = 0;

    for (; t < n_full; t += gstride, cur ^= 1) {
        const int tn = t + gstride;            // uniform across block
        if (tn < n_full) {
            stage_tile(pred, tgt, tn, buf[cur ^ 1], tid);
            asm volatile("s_waitcnt vmcnt(6)" ::: "memory");  // cur's 6 done
        } else {
            asm volatile("s_waitcnt vmcnt(0)" ::: "memory");
        }
        __builtin_amdgcn_s_barrier();          // buf[cur] visible to all waves

        const float* lds_p = buf[cur];
        const float* lds_t = buf[cur] + LDS_T_OFF;

        // ---- class softmax partials: 20 logits/thread in registers ----
        const float* cp = lds_p + cell_l * STRIDE + 5 + part * 20;
        float v[20];
        #pragma unroll
        for (int k = 0; k < 20; ++k) v[k] = cp[k];
        float mx = v[0];
        #pragma unroll
        for (int k = 1; k < 20; ++k) mx = fmaxf(mx, v[k]);
        mx = fmaxf(mx, __shfl_xor(mx, 1, 64));
        mx = fmaxf(mx, __shfl_xor(mx, 2, 64));
        float se = 0.f;
        #pragma unroll
        for (int k = 0; k < 20; ++k) se += __expf(v[k] - mx);
        se += __shfl_xor(se, 1, 64);
        se += __shfl_xor(se, 2, 64);

        if (part == 0) {
            const float* pc = lds_p + cell_l * STRIDE;
            const float* tc = lds_t + cell_l * 6;
            const float p0 = pc[0], t0 = tc[0];
            const float bce_base = fmaxf(p0, 0.f) + log1pf(__expf(-fabsf(p0)));
            if (t0 == 0.0f) { a_nobj += 1.f; a_bceno += bce_base; }
            if (t0 == 1.0f) {
                a_obj += 1.f;
                const int cell_g = t * TILE + cell_l;
                const int aidx = (cell_g / SSPAN) % 3;
                const float aw = aidx == 0 ? aw0 : (aidx == 1 ? aw1 : aw2);
                const float ah = aidx == 0 ? ah0 : (aidx == 1 ? ah1 : ah2);
                const float p1 = pc[1], p2 = pc[2], p3 = pc[3], p4 = pc[4];
                const float t1 = tc[1], t2 = tc[2], t3 = tc[3], t4 = tc[4];
                const float sx = 1.f / (1.f + __expf(-p1));
                const float sy = 1.f / (1.f + __expf(-p2));
                const float pw = __expf(p3) * aw, ph = __expf(p4) * ah;
                const float b1x1 = sx - pw * 0.5f, b1x2 = sx + pw * 0.5f;
                const float b1y1 = sy - ph * 0.5f, b1y2 = sy + ph * 0.5f;
                const float b2x1 = t1 - t3 * 0.5f, b2x2 = t1 + t3 * 0.5f;
                const float b2y1 = t2 - t4 * 0.5f, b2y2 = t2 + t4 * 0.5f;
                const float iw = fmaxf(fminf(b1x2, b2x2) - fmaxf(b1x1, b2x1), 0.f);
                const float ih = fmaxf(fminf(b1y2, b2y2) - fmaxf(b1y1, b2y1), 0.f);
                const float inter = iw * ih;
                const float uni = (b1x2 - b1x1) * (b1y2 - b1y1)
                                + (b2x2 - b2x1) * (b2y2 - b2y1) - inter;
                const float iou = inter / (uni + 1e-16f);
                a_bceo += bce_base - p0 * iou;
                const float lw = logf(1e-16f + t3 / aw);
                const float lh = logf(1e-16f + t4 / ah);
                const float d0 = sx - t1, d1 = sy - t2, d2 = p3 - lw, d3 = p4 - lh;
                a_box += d0 * d0 + d1 * d1 + d2 * d2 + d3 * d3;
                const int label = (int)tc[5];
                a_cls += (mx + __logf(se)) - pc[5 + label];
            }
        }
        asm volatile("" ::: "memory");         // no LDS reads sink past here
        __builtin_amdgcn_s_barrier();          // all waves done with buf[cur]
    }

    // ---- tail cells (n_rem < 64): block 0 only, direct global reads ----
    if (blockIdx.x == 0 && n_rem > 0 && cell_l < n_rem) {
        const int cell_g = n_full * TILE + cell_l;
        const float* cp = pred + (size_t)cell_g * STRIDE + 5 + part * 20;
        float v[20];
        #pragma unroll
        for (int k = 0; k < 20; ++k) v[k] = cp[k];
        float mx = v[0];
        #pragma unroll
        for (int k = 1; k < 20; ++k) mx = fmaxf(mx, v[k]);
        mx = fmaxf(mx, __shfl_xor(mx, 1, 64));
        mx = fmaxf(mx, __shfl_xor(mx, 2, 64));
        float se = 0.f;
        #pragma unroll
        for (int k = 0; k < 20; ++k) se += __expf(v[k] - mx);
        se += __shfl_xor(se, 1, 64);
        se += __shfl_xor(se, 2, 64);
        if (part == 0) {
            const float* pc = pred + (size_t)cell_g * STRIDE;
            const float* tc = tgt + (size_t)cell_g * 6;
            const float p0 = pc[0], t0 = tc[0];
            const float bce_base = fmaxf(p0, 0.f) + log1pf(__expf(-fabsf(p0)));
            if (t0 == 0.0f) { a_nobj += 1.f; a_bceno += bce_base; }
            if (t0 == 1.0f) {
                a_obj += 1.f;
                const int aidx = (cell_g / SSPAN) % 3;
                const float aw = aidx == 0 ? aw0 : (aidx == 1 ? aw1 : aw2);
                const float ah = aidx == 0 ? ah0 : (aidx == 1 ? ah1 : ah2);
                const float p1 = pc[1], p2 = pc[2], p3 = pc[3], p4 = pc[4];
                const float t1 = tc[1], t2 = tc[2], t3 = tc[3], t4 = tc[4];
                const float sx = 1.f / (1.f + __expf(-p1));
                const float sy = 1.f / (1.f + __expf(-p2));
                const float pw = __expf(p3) * aw, ph = __expf(p4) * ah;
                const float b1x1 = sx - pw * 0.5f, b1x2 = sx + pw * 0.5f;
                const float b1y1 = sy - ph * 0.5f, b1y2 = sy + ph * 0.5f;
                const float b2x1 = t1 - t3 * 0.5f, b2x2 = t1 + t3 * 0.5f;
                const float b2y1 = t2 - t4 * 0.5f, b2y2 = t2 + t4 * 0.5f;
                const float iw = fmaxf(fminf(b1x2, b2x2) - fmaxf(b1x1, b2x1), 0.f);
                const float ih = fmaxf(fminf(b1y2, b2y2) - fmaxf(b1y1, b2y1), 0.f);
                const float inter = iw * ih;
                const float uni = (b1x2 - b1x1) * (b1y2 - b1y1)
                                + (b2x2 - b2x1) * (b2y2 - b2y1) - inter;
                const float iou = inter / (uni + 1e-16f);
                a_bceo += bce_base - p0 * iou;
                const float lw = logf(1e-16f + t3 / aw);
                const float lh = logf(1e-16f + t4 / ah);
                const float d0 = sx - t1, d1 = sy - t2, d2 = p3 - lw, d3 = p4 - lh;
                a_box += d0 * d0 + d1 * d1 + d2 * d2 + d3 * d3;
                const int label = (int)tc[5];
                a_cls += (mx + __logf(se)) - pc[5 + label];
            }
        }
    }

    // ---- block reduction -> per-block partial ----
    float vals[6] = {a_obj, a_nobj, a_bceo, a_bceno, a_box, a_cls};
    #pragma unroll
    for (int k = 0; k < 6; ++k) {
        const float r = wave_reduce(vals[k]);
        if (lane == 0) red[wid][k] = r;
    }
    __syncthreads();
    if (tid == 0) {
        #pragma unroll
        for (int k = 0; k < 6; ++k)
            partial[blockIdx.x * 6 + k] =
                red[0][k] + red[1][k] + red[2][k] + red[3][k];
    }
}

__global__ __launch_bounds__(NTHREADS) void loss_final(
    const float* __restrict__ partial, int nblocks, float* __restrict__ out)
{
    __shared__ float red[4][6];
    const int tid = threadIdx.x, lane = tid & 63, wid = tid >> 6;
    float s[6] = {0.f, 0.f, 0.f, 0.f, 0.f, 0.f};
    for (int i = tid; i < nblocks; i += NTHREADS) {
        #pragma unroll
        for (int k = 0; k < 6; ++k) s[k] += partial[i * 6 + k];
    }
    #pragma unroll
    for (int k = 0; k < 6; ++k) {
        const float r = wave_reduce(s[k]);
        if (lane == 0) red[wid][k] = r;
    }
    __syncthreads();
    if (tid == 0) {
        float t[6];
        #pragma unroll
        for (int k = 0; k < 6; ++k)
            t[k] = red[0][k] + red[1][k] + red[2][k] + red[3][k];
        const float n_obj = t[0], n_noobj = t[1];
        out[0] = t[2] / n_obj + t[3] / n_noobj
               + t[4] / (4.f * n_obj) + t[5] / n_obj;
    }
}

extern "C" void kernel_launch(void* const* d_in, const int* in_sizes, int n_in,
                              void* d_out, int out_size, void* d_ws, size_t ws_size,
                              hipStream_t stream) {
    const float* pred    = (const float*)d_in[0];
    const float* tgt     = (const float*)d_in[1];
    const float* anchors = (const float*)d_in[2];
    float* out = (float*)d_out;

    const int n_cells = in_sizes[1] / 6;          // 259584
    const int n_full  = n_cells / TILE;           // 4056
    const int n_rem   = n_cells % TILE;           // 0 for this shape
    int grid = n_full < MAXGRID ? n_full : MAXGRID;
    if (grid < 1) grid = 1;
    float* partial = (float*)d_ws;

    loss_partial<<<grid, NTHREADS, 0, stream>>>(pred, tgt, anchors, partial,
                                                n_full, n_rem);
    loss_final<<<1, NTHREADS, 0, stream>>>(partial, grid, out);
}